// Round 7
// baseline (133.351 us; speedup 1.0000x reference)
//
#include <hip/hip_runtime.h>

#define N2 4096
#define D 128
#define TAU_INV 10.0f
#define K2 14.4269504088896340736f   // TAU_INV * log2(e)
#define MAIN_BLOCKS 2048             // 64 i-tiles (64 rows) x 32 j-slices (128 cols)

typedef __attribute__((ext_vector_type(8))) short bf16x8;
typedef __attribute__((ext_vector_type(4))) float floatx4;

__device__ __forceinline__ short f2bf(float f) {
    unsigned u = __float_as_uint(f);
    u = (u + 0x7fff + ((u >> 16) & 1)) >> 16;   // RNE
    return (short)u;
}

// Normalize p = concat(z_i,z_j) -> bf16 qb, labels; zero stats (se|sp) + ticket.
__global__ __launch_bounds__(256) void prep_kernel(const float* __restrict__ zi,
                                                   const float* __restrict__ zj,
                                                   const long long* __restrict__ y,
                                                   short* __restrict__ qb,
                                                   int* __restrict__ labels,
                                                   float* __restrict__ stats,
                                                   int* __restrict__ ticket) {
    int b = blockIdx.x;                 // 512 blocks, 8 rows each
    int tid = threadIdx.x;
    int wave = tid >> 6, lane = tid & 63;
    int l32 = lane & 31;
    int row = b * 8 + wave * 2 + (lane >> 5);
    const float* src = (row < 2048) ? (zi + row * D) : (zj + (row - 2048) * D);
    float4 v = ((const float4*)src)[l32];
    float ss = v.x * v.x + v.y * v.y + v.z * v.z + v.w * v.w;
    #pragma unroll
    for (int m = 1; m < 32; m <<= 1) ss += __shfl_xor(ss, m);
    float inv = rsqrtf(ss);             // ||p|| ~ sqrt(128) >> eps
    short4 o;
    o.x = f2bf(v.x * inv); o.y = f2bf(v.y * inv);
    o.z = f2bf(v.z * inv); o.w = f2bf(v.w * inv);
    ((short4*)(qb + row * D))[l32] = o;
    if (tid < 8) { int r2 = b * 8 + tid; labels[r2] = (int)y[r2 & 2047]; }
    if (tid < 16) stats[b * 16 + tid] = 0.f;     // 8192 floats = se | sp
    if (b == 0 && tid == 0) *ticket = 0;
}

// Fused sim-GEMM + masked-softmax row stats + last-block finish.
// 16x16x32 MFMA path for full occupancy: wave tile = 16 i-rows x 128 j-cols
// (8 subtiles of 16, K=128 = 4 MFMAs). Block = 4 waves stacked in i (64 rows).
// A/B frag: row/col = lane&15, k = (lane>>4)*8 + j. C/D: col=lane&15,
// row=(lane>>4)*4+reg. VGPR target 64 -> 8 waves/SIMD resident.
__global__ __launch_bounds__(256, 8) void main_kernel(const short* __restrict__ qb,
                                                      const int* __restrict__ labels,
                                                      float* __restrict__ stats,
                                                      int* __restrict__ ticket,
                                                      float* __restrict__ out) {
    int tid = threadIdx.x;
    int wave = tid >> 6, lane = tid & 63;
    int col = lane & 15, quad = lane >> 4;
    int it = blockIdx.x >> 5, js = blockIdx.x & 31;
    int i0 = it * 64 + wave * 16;
    int jbase = js * 128;

    const short* ap = qb + (i0 + col) * D + quad * 8;
    bf16x8 af[4];
    #pragma unroll
    for (int f = 0; f < 4; ++f) af[f] = *(const bf16x8*)(ap + f * 32);

    int rl[4];
    #pragma unroll
    for (int r = 0; r < 4; ++r) rl[r] = labels[i0 + quad * 4 + r];

    float se[4] = {0.f, 0.f, 0.f, 0.f};
    float sp[4] = {0.f, 0.f, 0.f, 0.f};

    #pragma unroll 1
    for (int sub = 0; sub < 8; ++sub) {
        int j0 = jbase + sub * 16;
        const short* bp = qb + (j0 + col) * D + quad * 8;
        bf16x8 bf[4];
        #pragma unroll
        for (int f = 0; f < 4; ++f) bf[f] = *(const bf16x8*)(bp + f * 32);

        floatx4 acc = {0.f, 0.f, 0.f, 0.f};
        #pragma unroll
        for (int f = 0; f < 4; ++f)
            acc = __builtin_amdgcn_mfma_f32_16x16x32_bf16(af[f], bf[f], acc, 0, 0, 0);

        int jcol = j0 + col;
        int cl = labels[jcol];
        #pragma unroll
        for (int r = 0; r < 4; ++r) {
            int rowr = i0 + quad * 4 + r;
            bool self = (rowr == jcol);
            float e = __builtin_amdgcn_exp2f(acc[r] * K2);
            se[r] += self ? 0.f : e;
            bool pos = (rl[r] == cl) && !self;
            sp[r] += pos ? acc[r] : 0.f;   // raw dot; TAU_INV applied in finish
        }
    }

    // reduce across the 16 cols (lanes sharing quad) and accumulate
    #pragma unroll
    for (int r = 0; r < 4; ++r) {
        float a = se[r], b = sp[r];
        #pragma unroll
        for (int m = 1; m < 16; m <<= 1) {
            a += __shfl_xor(a, m);
            b += __shfl_xor(b, m);
        }
        if (col == 0) {
            int rowr = i0 + quad * 4 + r;
            atomicAdd(&stats[rowr], a);
            atomicAdd(&stats[N2 + rowr], b);
        }
    }

    // ---- last-block finish (ticket) ----
    __shared__ int is_last;
    __syncthreads();
    if (tid == 0) {
        __threadfence();                          // release our atomics
        int old = atomicAdd(ticket, 1);
        is_last = (old == MAIN_BLOCKS - 1);
    }
    __syncthreads();
    if (!is_last) return;
    __threadfence();                              // acquire others' atomics

    __shared__ int hist[10];
    if (tid < 10) hist[tid] = 0;
    __syncthreads();
    for (int i = tid; i < 2048; i += 256) atomicAdd(&hist[labels[i]], 1);
    __syncthreads();

    float local = 0.f;
    for (int r = tid; r < N2; r += 256) {
        float cnt = (float)(2 * hist[labels[r]] - 1);
        local += (stats[N2 + r] * TAU_INV) / cnt - __logf(stats[r]);
    }
    #pragma unroll
    for (int m = 1; m < 64; m <<= 1) local += __shfl_xor(local, m);
    __shared__ float wsum[4];
    if (lane == 0) wsum[wave] = local;
    __syncthreads();
    if (tid == 0) out[0] = -(wsum[0] + wsum[1] + wsum[2] + wsum[3]) * (1.0f / (float)N2);
}

extern "C" void kernel_launch(void* const* d_in, const int* in_sizes, int n_in,
                              void* d_out, int out_size, void* d_ws, size_t ws_size,
                              hipStream_t stream) {
    const float*     zi = (const float*)d_in[0];
    const float*     zj = (const float*)d_in[1];
    const long long* y  = (const long long*)d_in[2];
    float* out = (float*)d_out;

    char* ws = (char*)d_ws;
    short* qb     = (short*)ws;                               // 1 MB
    int*   labels = (int*)(ws + N2 * D * sizeof(short));      // 16 KB
    float* stats  = (float*)(ws + N2 * D * sizeof(short) + N2 * sizeof(int)); // 32 KB
    int*   ticket = (int*)(stats + 2 * N2);

    prep_kernel<<<512, 256, 0, stream>>>(zi, zj, y, qb, labels, stats, ticket);
    main_kernel<<<MAIN_BLOCKS, 256, 0, stream>>>(qb, labels, stats, ticket, out);
}